// Round 3
// baseline (1841.684 us; speedup 1.0000x reference)
//
#include <hip/hip_runtime.h>
#include <hip/hip_bf16.h>
#include <hip/hip_fp16.h>

#define VV 5000
#define NTOP 50
#define ENH 200
#define NEMB 200
#define OD 40
#define MP 5120

typedef __attribute__((ext_vector_type(8))) short short8;
typedef __attribute__((ext_vector_type(4))) float f32x4;

// ---------------- workspace layout (bytes) ----------------
constexpr size_t OFF_R      = 0;          // 5000 f (atomic accum, zeroed)
constexpr size_t OFF_S      = 20224;      // 512 f (atomic accum, zeroed)
constexpr size_t OFF_SCAL   = 22528;      // 64 f: [0]=eps [1]=1/eps [2]=loss_KL [3]=ecr_dot
constexpr size_t OFF_PHIA   = 22784;      // 5000 f (zeroed = phi0)
constexpr size_t OFF_PHIB   = 43008;      // 5000 f
constexpr size_t OFF_ROWS   = 63232;      // S1[40] S2[40] S3[40]
constexpr size_t OFF_PARTS  = 63744;      // 2*32*64 f (ECR partials, sign-tagged dbl-buffer)
constexpr size_t OFF_MUPRE  = 80128;      // 50*40 f
constexpr size_t OFF_LVPRE  = 88320;
constexpr size_t OFF_E1T    = 96512;      // 200*40 f  [k][i]
constexpr size_t OFF_E2T    = 128512;
constexpr size_t OFF_THRED  = 160512;     // 40*50 f
constexpr size_t OFF_BOWRED = 168512;     // 40*5000 f (atomic accum, zeroed)
constexpr size_t ZERO_BYTES = 968576;     // everything below PVT is zeroed each call
constexpr size_t OFF_PVT    = 968576;     // 48*5120 bf16 (proj_V transposed, padded)
constexpr size_t OFF_XB     = 1460096;    // 5120*512 bf16 (bow.T, padded rows)
constexpr size_t OFF_CE     = 6702976;    // 5000*5000 fp16 (C/eps)
constexpr size_t OFF_COST   = 56702976;   // 50*5000 f
constexpr size_t OFF_KM     = 57702976;
constexpr size_t OFF_BETA   = 58702976;
constexpr size_t OFF_RN     = 59702976;   // 40*5000 f

// ============ K1: transpose bow -> Xb(bf16), row norms r, col sums s ============
__global__ __launch_bounds__(256) void k1_stats(const float* __restrict__ bow,
    __hip_bfloat16* __restrict__ Xb, float* __restrict__ r, float* __restrict__ s){
  __shared__ float lds[64][129];
  const int t = threadIdx.x;
  const int i0 = blockIdx.x * 128, d0 = blockIdx.y * 64;
  #pragma unroll
  for (int m = 0; m < 32; ++m){
    int idx = m*256 + t;
    int di = idx >> 7;
    int ii = idx & 127;
    int gi = i0 + ii;
    lds[di][ii] = (gi < VV) ? bow[(size_t)(d0+di)*VV + gi] : 0.f;
  }
  __syncthreads();
  if (t < 128 && (i0 + t) < VV){
    float acc = 0.f;
    for (int di = 0; di < 64; ++di){ float v = lds[di][t]; acc += v*v; }
    atomicAdd(&r[i0+t], acc);
  }
  if (t < 64){
    float acc = 0.f;
    for (int ii = 0; ii < 128; ++ii) acc += lds[t][ii];
    atomicAdd(&s[d0+t], acc);
  }
  __syncthreads();
  #pragma unroll
  for (int m = 0; m < 32; ++m){
    int idx = m*256 + t;
    int ii = idx >> 6;
    int dd = idx & 63;
    Xb[(size_t)(i0+ii)*512 + d0 + dd] = __float2bfloat16(lds[dd][ii]);
  }
}

// ============ K2: eps from closed-form mean(C) ============
__global__ __launch_bounds__(256) void k2_eps(const float* __restrict__ r,
    const float* __restrict__ s, float* __restrict__ scal){
  const int t = threadIdx.x;
  float a = 0.f, b = 0.f;
  for (int i = t; i < VV; i += 256) a += r[i];
  for (int d = t; d < 512; d += 256){ float v = s[d]; b += v*v; }
  #pragma unroll
  for (int off = 32; off; off >>= 1){
    a += __shfl_down(a, off, 64);
    b += __shfl_down(b, off, 64);
  }
  __shared__ float ra[4], rb[4];
  int lane = t & 63, w = t >> 6;
  if (lane == 0){ ra[w] = a; rb[w] = b; }
  __syncthreads();
  if (t == 0){
    float sa = ra[0]+ra[1]+ra[2]+ra[3];
    float sb = rb[0]+rb[1]+rb[2]+rb[3];
    float meanC = 2.f*sa/(float)VV - 2.f*sb/((float)VV*(float)VV);
    float eps = meanC / logf(30.f) + 1e-6f;
    scal[0] = eps;
    scal[1] = 1.f/eps;
  }
}

// ============ K3: Ce = (r_i + r_j - 2*X X^T)/eps as fp16, bf16 MFMA ============
__global__ __launch_bounds__(256) void k3_gemm(const __hip_bfloat16* __restrict__ Xb,
    const float* __restrict__ r, const float* __restrict__ scal, __half* __restrict__ Ce){
  __shared__ __hip_bfloat16 As[128*72];
  __shared__ __hip_bfloat16 Bs[128*72];
  const int t = threadIdx.x;
  const int i0 = blockIdx.x * 128, j0 = blockIdx.y * 128;
  const int lane = t & 63, w = t >> 6;
  const int wr = w >> 1, wc = w & 1;
  const int m16 = lane & 15, q4 = lane >> 4;
  f32x4 acc[4][4];
  #pragma unroll
  for (int a = 0; a < 4; ++a)
    #pragma unroll
    for (int b = 0; b < 4; ++b) acc[a][b] = (f32x4){0.f,0.f,0.f,0.f};
  const int srow = t >> 3, sseg = t & 7;
  for (int kc = 0; kc < 512; kc += 64){
    __syncthreads();
    #pragma unroll
    for (int m = 0; m < 4; ++m){
      int row = m*32 + srow;
      uint4 va = *(const uint4*)(Xb + (size_t)(i0+row)*512 + kc + sseg*8);
      *(uint4*)(As + row*72 + sseg*8) = va;
      uint4 vb = *(const uint4*)(Xb + (size_t)(j0+row)*512 + kc + sseg*8);
      *(uint4*)(Bs + row*72 + sseg*8) = vb;
    }
    __syncthreads();
    #pragma unroll
    for (int ks = 0; ks < 64; ks += 32){
      short8 af[4], bf[4];
      #pragma unroll
      for (int f = 0; f < 4; ++f){
        af[f] = *(const short8*)(As + (wr*64 + f*16 + m16)*72 + ks + q4*8);
        bf[f] = *(const short8*)(Bs + (wc*64 + f*16 + m16)*72 + ks + q4*8);
      }
      #pragma unroll
      for (int fr = 0; fr < 4; ++fr)
        #pragma unroll
        for (int fc = 0; fc < 4; ++fc)
          acc[fr][fc] = __builtin_amdgcn_mfma_f32_16x16x32_bf16(af[fr], bf[fc], acc[fr][fc], 0, 0, 0);
    }
  }
  const float inv_eps = scal[1];
  #pragma unroll
  for (int fr = 0; fr < 4; ++fr){
    int rbase = i0 + wr*64 + fr*16 + q4*4;
    #pragma unroll
    for (int fc = 0; fc < 4; ++fc){
      int col = j0 + wc*64 + fc*16 + m16;
      if (col < VV){
        float rc = r[col];
        #pragma unroll
        for (int q = 0; q < 4; ++q){
          int row = rbase + q;
          if (row < VV){
            float val = (r[row] + rc - 2.f*acc[fr][fc][q]) * inv_eps;
            Ce[(size_t)row*VV + col] = __float2half(val);
          }
        }
      }
    }
  }
}

// ============ K4: one symmetric-Sinkhorn sweep (phi = f/eps) ============
__global__ __launch_bounds__(256) void k4_sweep(const __half* __restrict__ Ce,
    const float* __restrict__ phi_in, float* __restrict__ phi_out){
  const int t = threadIdx.x;
  const int i0 = blockIdx.x * 8;
  float acc[8];
  #pragma unroll
  for (int rr = 0; rr < 8; ++rr) acc[rr] = 0.f;
  for (int c = t; c < 2500; c += 256){
    float2 ph = ((const float2*)phi_in)[c];
    #pragma unroll
    for (int rr = 0; rr < 8; ++rr){
      __half2 h2 = *((const __half2*)(Ce + (size_t)(i0+rr)*VV) + c);
      float2 ce = __half22float2(h2);
      acc[rr] += __expf(ph.x - ce.x) + __expf(ph.y - ce.y);
    }
  }
  #pragma unroll
  for (int rr = 0; rr < 8; ++rr)
    #pragma unroll
    for (int off = 32; off; off >>= 1)
      acc[rr] += __shfl_down(acc[rr], off, 64);
  __shared__ float red[4][8];
  int lane = t & 63, w = t >> 6;
  if (lane == 0){
    #pragma unroll
    for (int rr = 0; rr < 8; ++rr) red[w][rr] = acc[rr];
  }
  __syncthreads();
  if (t < 8){
    float ssum = red[0][t] + red[1][t] + red[2][t] + red[3][t];
    const float loga = -8.517193191416238f;   // -log(5000)
    float lse = __logf(ssum);
    phi_out[i0 + t] = 0.5f*(phi_in[i0 + t] + loga - lse);
  }
}

// ============ K5p: proj_V -> transposed padded bf16 [48][5120] ============
__global__ __launch_bounds__(256) void k5p_pvt(const float* __restrict__ projV,
    __hip_bfloat16* __restrict__ pvt){
  int idx = blockIdx.x*256 + threadIdx.x;
  if (idx >= 48*MP) return;
  int n = idx / MP, j = idx - n*MP;
  float v = (n < OD && j < VV) ? projV[(size_t)j*OD + n] : 0.f;
  pvt[idx] = __float2bfloat16(v);
}

// ============ K5: bow_reduced = (P @ proj_V)^T via MFMA, P on the fly ============
__global__ __launch_bounds__(256) void k5_bowred(const __half* __restrict__ Ce,
    const float* __restrict__ phi, const __hip_bfloat16* __restrict__ pvt,
    float* __restrict__ br){
  __shared__ __hip_bfloat16 As[128*72];
  __shared__ __hip_bfloat16 Bs[48*72];
  const int t = threadIdx.x;
  const int i0 = blockIdx.x * 128;
  const int k0 = blockIdx.y * 320;
  const int lane = t & 63, w = t >> 6;
  const int m16 = lane & 15, q4 = lane >> 4;
  f32x4 acc[2][3];
  #pragma unroll
  for (int a = 0; a < 2; ++a)
    #pragma unroll
    for (int b = 0; b < 3; ++b) acc[a][b] = (f32x4){0.f,0.f,0.f,0.f};
  for (int kc = k0; kc < k0 + 320; kc += 64){
    __syncthreads();
    #pragma unroll
    for (int m = 0; m < 32; ++m){
      int idx = m*256 + t;
      int row = idx >> 6, c = idx & 63;
      int gi = i0 + row, j2 = kc + c;
      float p = 0.f;
      if (gi < VV && j2 < VV){
        float ce = __half2float(Ce[(size_t)gi*VV + j2]);
        p = __expf(phi[gi] + phi[j2] - ce);
      }
      As[row*72 + c] = __float2bfloat16(p);
    }
    #pragma unroll
    for (int m = 0; m < 12; ++m){
      int idx = m*256 + t;
      int row = idx >> 6, c = idx & 63;
      Bs[row*72 + c] = pvt[(size_t)row*MP + kc + c];
    }
    __syncthreads();
    #pragma unroll
    for (int ks = 0; ks < 64; ks += 32){
      short8 af[2], bf[3];
      #pragma unroll
      for (int f = 0; f < 2; ++f)
        af[f] = *(const short8*)(As + (w*32 + f*16 + m16)*72 + ks + q4*8);
      #pragma unroll
      for (int f = 0; f < 3; ++f)
        bf[f] = *(const short8*)(Bs + (f*16 + m16)*72 + ks + q4*8);
      #pragma unroll
      for (int fr = 0; fr < 2; ++fr)
        #pragma unroll
        for (int fc = 0; fc < 3; ++fc)
          acc[fr][fc] = __builtin_amdgcn_mfma_f32_16x16x32_bf16(af[fr], bf[fc], acc[fr][fc], 0, 0, 0);
    }
  }
  #pragma unroll
  for (int fr = 0; fr < 2; ++fr){
    int rbase = i0 + w*32 + fr*16 + q4*4;
    #pragma unroll
    for (int fc = 0; fc < 3; ++fc){
      int col = fc*16 + m16;
      if (col < OD){
        #pragma unroll
        for (int q = 0; q < 4; ++q){
          int row = rbase + q;
          if (row < VV) atomicAdd(&br[(size_t)col*VV + row], acc[fr][fc][q]);
        }
      }
    }
  }
}

// ============ K6: e1^T = softplus(bow_reduced @ W1^T + b1) ============
__global__ __launch_bounds__(256) void k6_e1(const float* __restrict__ br,
    const float* __restrict__ W1, const float* __restrict__ b1, float* __restrict__ e1t){
  const int t = threadIdx.x;
  const int lane = t & 63, w = t >> 6;
  const int k = blockIdx.x*4 + w;
  float acc[OD];
  #pragma unroll
  for (int i = 0; i < OD; ++i) acc[i] = 0.f;
  const float4* w4p = (const float4*)(W1 + (size_t)k*VV);
  for (int f4 = lane; f4 < 1250; f4 += 64){
    float4 wv = w4p[f4];
    #pragma unroll
    for (int i = 0; i < OD; ++i){
      float4 bv = ((const float4*)(br + (size_t)i*VV))[f4];
      acc[i] += bv.x*wv.x + bv.y*wv.y + bv.z*wv.z + bv.w*wv.w;
    }
  }
  #pragma unroll
  for (int i = 0; i < OD; ++i)
    #pragma unroll
    for (int off = 32; off; off >>= 1)
      acc[i] += __shfl_down(acc[i], off, 64);
  __shared__ float red[4][OD];
  if (lane == 0){
    #pragma unroll
    for (int i = 0; i < OD; ++i) red[w][i] = acc[i];
  }
  __syncthreads();
  if (t < 160){
    int ww = t / OD, i = t - ww*OD;
    int kk = blockIdx.x*4 + ww;
    float x = red[ww][i] + b1[kk];
    float sp = (x > 20.f) ? x : log1pf(__expf(x));
    e1t[kk*OD + i] = sp;
  }
}

// ============ K7: e2^T = softplus(e1 @ W2^T + b2) ============
__global__ __launch_bounds__(256) void k7_e2(const float* __restrict__ e1t,
    const float* __restrict__ W2, const float* __restrict__ b2, float* __restrict__ e2t){
  const int t = threadIdx.x;
  const int lane = t & 63, w = t >> 6;
  const int k = blockIdx.x*4 + w;
  float acc[OD];
  #pragma unroll
  for (int i = 0; i < OD; ++i) acc[i] = 0.f;
  for (int j = lane; j < ENH; j += 64){
    float wv = W2[(size_t)k*ENH + j];
    #pragma unroll
    for (int i = 0; i < OD; ++i) acc[i] += e1t[j*OD + i] * wv;
  }
  #pragma unroll
  for (int i = 0; i < OD; ++i)
    #pragma unroll
    for (int off = 32; off; off >>= 1)
      acc[i] += __shfl_down(acc[i], off, 64);
  __shared__ float red[4][OD];
  if (lane == 0){
    #pragma unroll
    for (int i = 0; i < OD; ++i) red[w][i] = acc[i];
  }
  __syncthreads();
  if (t < 160){
    int ww = t / OD, i = t - ww*OD;
    int kk = blockIdx.x*4 + ww;
    float x = red[ww][i] + b2[kk];
    float sp = (x > 20.f) ? x : log1pf(__expf(x));
    e2t[kk*OD + i] = sp;
  }
}

// ============ K8a: mu_pre/lv_pre (stored [t50][i]) ============
__global__ __launch_bounds__(256) void k8a_mulv(const float* __restrict__ e2t,
    const float* __restrict__ Wmu, const float* __restrict__ bmu,
    const float* __restrict__ Wlv, const float* __restrict__ blv,
    float* __restrict__ mupre, float* __restrict__ lvpre){
  int id = blockIdx.x*256 + threadIdx.x;
  if (id >= NTOP*OD) return;
  int t50 = id / OD, i = id - t50*OD;
  float am = 0.f, al = 0.f;
  for (int kk = 0; kk < ENH; ++kk){
    float e = e2t[kk*OD + i];
    am += e * Wmu[t50*ENH + kk];
    al += e * Wlv[t50*ENH + kk];
  }
  mupre[t50*OD + i] = am + bmu[t50];
  lvpre[t50*OD + i] = al + blv[t50];
}

// ============ K8b: BN + KL + z/theta + small SNE(50) + theta_reduced (single WG) ============
__global__ __launch_bounds__(256) void k8b_theta(const float* __restrict__ mupre,
    const float* __restrict__ lvpre,
    const float* __restrict__ g_mu, const float* __restrict__ be_mu,
    const float* __restrict__ g_lv, const float* __restrict__ be_lv,
    const float* __restrict__ eps_noise, const float* __restrict__ projK,
    float* __restrict__ thred, float* __restrict__ d_out3, float* __restrict__ scal){
  __shared__ float mu[NTOP][OD];
  __shared__ float lv[NTOP][OD];
  __shared__ float th[OD][NTOP];
  __shared__ float C2[NTOP][NTOP];
  __shared__ float P2[NTOP][NTOP];
  __shared__ float f2[NTOP], nf[NTOP];
  __shared__ float sred[4];
  __shared__ float eps2s[2];
  const int t = threadIdx.x;
  if (t < NTOP){
    float m = 0.f;
    for (int i = 0; i < OD; ++i) m += mupre[t*OD + i];
    m *= (1.f/OD);
    float v = 0.f;
    for (int i = 0; i < OD; ++i){ float d = mupre[t*OD+i] - m; v += d*d; }
    v *= (1.f/OD);
    float sc = g_mu[t] * rsqrtf(v + 1e-5f);
    float sh = be_mu[t];
    for (int i = 0; i < OD; ++i) mu[t][i] = (mupre[t*OD+i] - m)*sc + sh;
    m = 0.f;
    for (int i = 0; i < OD; ++i) m += lvpre[t*OD + i];
    m *= (1.f/OD);
    v = 0.f;
    for (int i = 0; i < OD; ++i){ float d = lvpre[t*OD+i] - m; v += d*d; }
    v *= (1.f/OD);
    sc = g_lv[t] * rsqrtf(v + 1e-5f);
    sh = be_lv[t];
    for (int i = 0; i < OD; ++i) lv[t][i] = (lvpre[t*OD+i] - m)*sc + sh;
  }
  __syncthreads();
  { // KL divergence
    float kl = 0.f;
    if (t < OD){
      const float var2 = 1.f - 1.f/(float)NTOP;
      const float lv2 = logf(var2);
      float ssum = 0.f;
      for (int q = 0; q < NTOP; ++q){
        float l = lv[q][t];
        float m = mu[q][t];
        ssum += (__expf(l) + m*m)/var2 + lv2 - l;
      }
      kl = 0.5f*(ssum - (float)NTOP);
    }
    #pragma unroll
    for (int off = 32; off; off >>= 1) kl += __shfl_down(kl, off, 64);
    if ((t & 63) == 0) sred[t >> 6] = kl;
    __syncthreads();
    if (t == 0) scal[2] = (sred[0]+sred[1]+sred[2]+sred[3]) * (1.f/OD);
    __syncthreads();
  }
  if (t < OD){ // z + softmax
    float z[NTOP];
    float mx = -1e30f;
    for (int q = 0; q < NTOP; ++q){
      float val = mu[q][t] + eps_noise[t*NTOP + q]*__expf(0.5f*lv[q][t]);
      z[q] = val;
      mx = fmaxf(mx, val);
    }
    float ssum = 0.f;
    for (int q = 0; q < NTOP; ++q){ float e = __expf(z[q]-mx); z[q] = e; ssum += e; }
    float inv = 1.f/ssum;
    for (int q = 0; q < NTOP; ++q) th[t][q] = z[q]*inv;
  }
  __syncthreads();
  { // C2 + mean
    float csum = 0.f;
    for (int pr = t; pr < NTOP*NTOP; pr += 256){
      int a = pr / NTOP, b = pr - (pr/NTOP)*NTOP;
      float ss = 0.f;
      for (int i = 0; i < OD; ++i){ float d = th[i][a] - th[i][b]; ss += d*d; }
      C2[a][b] = ss;
      csum += ss;
    }
    #pragma unroll
    for (int off = 32; off; off >>= 1) csum += __shfl_down(csum, off, 64);
    if ((t & 63) == 0) sred[t >> 6] = csum;
    __syncthreads();
    if (t == 0){
      float meanC = (sred[0]+sred[1]+sred[2]+sred[3]) / ((float)NTOP*NTOP);
      float e2 = meanC / logf(30.f) + 1e-6f;
      eps2s[0] = e2; eps2s[1] = 1.f/e2;
    }
  }
  if (t < NTOP) f2[t] = 0.f;
  __syncthreads();
  const float loga2 = -logf((float)NTOP);
  for (int it = 0; it < 20; ++it){
    if (t < NTOP){
      float ie = eps2s[1];
      float ssum = 0.f;
      for (int sI = 0; sI < NTOP; ++sI)
        ssum += __expf((f2[sI] - C2[t][sI]) * ie);
      float lse = __logf(ssum);
      nf[t] = 0.5f*(f2[t] + eps2s[0]*(loga2 - lse));
    }
    __syncthreads();
    if (t < NTOP) f2[t] = nf[t];
    __syncthreads();
  }
  for (int pr = t; pr < NTOP*NTOP; pr += 256){
    int a = pr / NTOP, b = pr - (pr/NTOP)*NTOP;
    P2[a][b] = __expf((f2[a] + f2[b] - C2[a][b]) * eps2s[1]);
  }
  __syncthreads();
  for (int o = t; o < NTOP*OD; o += 256){
    int t50 = o / OD, kk = o - (o/OD)*OD;
    float ssum = 0.f;
    for (int sI = 0; sI < NTOP; ++sI)
      ssum += P2[t50][sI] * projK[sI*OD + kk];
    thred[kk*NTOP + t50] = ssum;
    d_out3[kk*NTOP + t50] = ssum;
  }
}

// ============ K10: cost, Km=exp(-20c), beta=softmax(-5c over topics) ============
__global__ __launch_bounds__(256) void k10_cost(const float* __restrict__ temb,
    const float* __restrict__ wemb, float* __restrict__ cost, float* __restrict__ Km,
    float* __restrict__ beta){
  __shared__ float Tt[100][52];
  __shared__ float wed[100][68];
  __shared__ float sc[52][64];
  __shared__ float tn[52];
  __shared__ float wn[64];
  const int t = threadIdx.x;
  const int j0 = blockIdx.x * 64;
  const int tg = t >> 4, jg = t & 15;
  float am[4][4];
  #pragma unroll
  for (int a = 0; a < 4; ++a)
    #pragma unroll
    for (int b = 0; b < 4; ++b) am[a][b] = 0.f;
  float tnp = 0.f, wnp = 0.f;
  for (int c = 0; c < 2; ++c){
    __syncthreads();
    const int dbase = c*100;
    for (int idx = t; idx < NTOP*100; idx += 256){
      int t50 = idx / 100, d = idx - t50*100;
      Tt[d][t50] = temb[t50*NEMB + dbase + d];
    }
    for (int idx = t; idx < 64*100; idx += 256){
      int j = idx / 100, d = idx - j*100;
      int gj = j0 + j;
      wed[d][j] = (gj < VV) ? wemb[(size_t)gj*NEMB + dbase + d] : 0.f;
    }
    __syncthreads();
    if (t < NTOP){
      float a = 0.f;
      for (int d = 0; d < 100; ++d){ float v = Tt[d][t]; a += v*v; }
      tnp += a;
    }
    if (t >= 64 && t < 128){
      int j = t - 64;
      float a = 0.f;
      for (int d = 0; d < 100; ++d){ float v = wed[d][j]; a += v*v; }
      wnp += a;
    }
    if (t < 208){
      for (int d = 0; d < 100; ++d){
        const float4 tv = *(const float4*)(&Tt[d][tg*4]);
        const float4 wv = *(const float4*)(&wed[d][jg*4]);
        am[0][0] += tv.x*wv.x; am[0][1] += tv.x*wv.y; am[0][2] += tv.x*wv.z; am[0][3] += tv.x*wv.w;
        am[1][0] += tv.y*wv.x; am[1][1] += tv.y*wv.y; am[1][2] += tv.y*wv.z; am[1][3] += tv.y*wv.w;
        am[2][0] += tv.z*wv.x; am[2][1] += tv.z*wv.y; am[2][2] += tv.z*wv.z; am[2][3] += tv.z*wv.w;
        am[3][0] += tv.w*wv.x; am[3][1] += tv.w*wv.y; am[3][2] += tv.w*wv.z; am[3][3] += tv.w*wv.w;
      }
    }
  }
  if (t < NTOP) tn[t] = tnp;
  if (t >= 64 && t < 128) wn[t-64] = wnp;
  __syncthreads();
  if (t < 208){
    #pragma unroll
    for (int a = 0; a < 4; ++a){
      int t50 = tg*4 + a;
      if (t50 < NTOP){
        float tv = tn[t50];
        float cc[4];
        #pragma unroll
        for (int b = 0; b < 4; ++b) cc[b] = tv + wn[jg*4+b] - 2.f*am[a][b];
        int gj = j0 + jg*4;
        if (gj + 3 < VV){
          *(float4*)(cost + (size_t)t50*VV + gj) = make_float4(cc[0],cc[1],cc[2],cc[3]);
          *(float4*)(Km + (size_t)t50*VV + gj) =
              make_float4(__expf(-20.f*cc[0]), __expf(-20.f*cc[1]),
                          __expf(-20.f*cc[2]), __expf(-20.f*cc[3]));
        }
        #pragma unroll
        for (int b = 0; b < 4; ++b) sc[t50][jg*4+b] = -5.f*cc[b];
      }
    }
  }
  __syncthreads();
  if (t < 64){
    int gj = j0 + t;
    if (gj < VV){
      float mx = -1e30f;
      for (int q = 0; q < NTOP; ++q) mx = fmaxf(mx, sc[q][t]);
      float ssum = 0.f;
      for (int q = 0; q < NTOP; ++q){ float e = __expf(sc[q][t]-mx); sc[q][t] = e; ssum += e; }
      float inv = 1.f/ssum;
      for (int q = 0; q < NTOP; ++q) beta[(size_t)q*VV + gj] = sc[q][t]*inv;
    }
  }
}

// ============ K11: ECR Sinkhorn, 32 co-resident WGs ============
// Flag-free sync: each WG stores its 50 per-topic partials into a
// double-buffered slot; readiness is carried in the SIGN BIT of each value
// (partials are >= 0). Slot for iteration it is buffer (it&1); the stored
// sign bit for that use is 1-((it>>1)&1), so reuse of a slot always flips
// the bit and the memset-0 initial state (+0.0, bit 0) reads as not-ready
// for it=0. Sense-reversing: a writer can't lap a reader by 2 iterations
// (it would need the reader's own it+1 partial first).
__global__ __launch_bounds__(256) void k11_ecr(const float* __restrict__ Km,
    const float* __restrict__ cost, float* __restrict__ parts,
    float* __restrict__ scal){
  const int t = threadIdx.x;
  const int b = blockIdx.x;                 // 0..31
  const int base = b*156 + (b < 8 ? b : 8);
  const int sz = 156 + (b < 8 ? 1 : 0);     // 157 for b<8 else 156
  __shared__ __align__(16) float us[56];
  __shared__ __align__(16) float varr[160];
  __shared__ float p5[5][52];
  __shared__ float redr[4];
  const int j1 = base + t;
  const bool ok1 = (t < sz);
  float kj1[52];
  #pragma unroll
  for (int q = 0; q < NTOP; ++q) kj1[q] = ok1 ? Km[(size_t)q*VV + j1] : 0.f;
  kj1[50] = 0.f; kj1[51] = 0.f;
  const int qq = t % NTOP;                  // topic for phase2 (t<250)
  const int stripe = t / NTOP;              // 0..4
  float kst[32];
  if (t < 250){
    #pragma unroll
    for (int n = 0; n < 32; ++n){
      int loc = stripe*32 + n;
      kst[n] = (loc < sz) ? Km[(size_t)qq*VV + base + loc] : 0.f;
    }
  }
  if (t < 56) us[t] = (t < NTOP) ? (1.f/(float)NTOP) : 0.f;
  if (t < 160) varr[t] = 0.f;
  __syncthreads();
  unsigned int* pslot = (unsigned int*)parts;
  for (int it = 0; it < 100; ++it){
    // phase 1: v_j = (1/V) / (Km^T u + 1e-16), 4 indep chains
    float w0 = 0.f, w1 = 0.f, w2 = 0.f, w3 = 0.f;
    #pragma unroll
    for (int q = 0; q < 52; q += 4){
      float4 u4 = *(const float4*)(us + q);
      w0 += kj1[q]*u4.x; w1 += kj1[q+1]*u4.y;
      w2 += kj1[q+2]*u4.z; w3 += kj1[q+3]*u4.w;
    }
    if (ok1) varr[t] = (1.f/(float)VV)/(((w0+w1)+(w2+w3)) + 1e-16f);
    __syncthreads();
    // phase 2: per-topic partial of Km v over this slice
    if (t < 250){
      float s0 = 0.f, s1 = 0.f, s2 = 0.f, s3 = 0.f;
      #pragma unroll
      for (int n = 0; n < 32; n += 4){
        float4 v4 = *(const float4*)(varr + stripe*32 + n);
        s0 += kst[n]*v4.x; s1 += kst[n+1]*v4.y;
        s2 += kst[n+2]*v4.z; s3 += kst[n+3]*v4.w;
      }
      p5[stripe][qq] = (s0+s1)+(s2+s3);
    }
    __syncthreads();
    const unsigned int sp = 1u - (((unsigned)it >> 1) & 1u);
    const int bi = it & 1;
    if (t < NTOP){
      float sm = p5[0][t]+p5[1][t]+p5[2][t]+p5[3][t]+p5[4][t];
      unsigned int uv = __float_as_uint(sm) | (sp << 31);
      __hip_atomic_store(&pslot[bi*2048 + b*64 + t], uv,
                         __ATOMIC_RELAXED, __HIP_MEMORY_SCOPE_AGENT);
      // poll all 32 slots concurrently
      float tot = 0.f;
      unsigned int done = 0u;
      while (done != 0xFFFFFFFFu){
        #pragma unroll
        for (int wg = 0; wg < 32; ++wg){
          if (!((done >> wg) & 1u)){
            unsigned int v = __hip_atomic_load(&pslot[bi*2048 + wg*64 + t],
                                               __ATOMIC_RELAXED, __HIP_MEMORY_SCOPE_AGENT);
            if ((v >> 31) == sp){
              tot += __uint_as_float(v & 0x7fffffffu);
              done |= (1u << wg);
            }
          }
        }
        if (done != 0xFFFFFFFFu) __builtin_amdgcn_s_sleep(1);
      }
      us[t] = (1.f/(float)NTOP)/(tot + 1e-16f);
    }
    __syncthreads();
  }
  // final: v = b/(Km^T u), partial of sum(u * Km * v^T * cost)
  float lsum = 0.f;
  if (ok1){
    float w0 = 0.f, w1 = 0.f, w2 = 0.f, w3 = 0.f;
    #pragma unroll
    for (int q = 0; q < 52; q += 4){
      float4 u4 = *(const float4*)(us + q);
      w0 += kj1[q]*u4.x; w1 += kj1[q+1]*u4.y;
      w2 += kj1[q+2]*u4.z; w3 += kj1[q+3]*u4.w;
    }
    float v = (1.f/(float)VV)/(((w0+w1)+(w2+w3)) + 1e-16f);
    float sacc = 0.f;
    #pragma unroll
    for (int q = 0; q < NTOP; ++q)
      sacc += us[q]*kj1[q]*cost[(size_t)q*VV + j1];
    lsum = sacc * v;
  }
  #pragma unroll
  for (int off = 32; off; off >>= 1) lsum += __shfl_down(lsum, off, 64);
  if ((t & 63) == 0) redr[t >> 6] = lsum;
  __syncthreads();
  if (t == 0) atomicAdd(&scal[3], redr[0]+redr[1]+redr[2]+redr[3]);
}

// ============ K12: R = theta_red @ beta, column BN ============
__global__ __launch_bounds__(256) void k12_reconA(const float* __restrict__ thred,
    const float* __restrict__ beta, const float* __restrict__ g_dec,
    const float* __restrict__ be_dec, float* __restrict__ Rn){
  __shared__ float trs[OD][NTOP];
  const int t = threadIdx.x;
  for (int o = t; o < OD*NTOP; o += 256) trs[o/NTOP][o - (o/NTOP)*NTOP] = thred[o];
  __syncthreads();
  int j = blockIdx.x*256 + t;
  if (j >= VV) return;
  float a[OD];
  #pragma unroll
  for (int i = 0; i < OD; ++i) a[i] = 0.f;
  for (int q = 0; q < NTOP; ++q){
    float bv = beta[(size_t)q*VV + j];
    #pragma unroll
    for (int i = 0; i < OD; ++i) a[i] += trs[i][q]*bv;
  }
  float m = 0.f;
  #pragma unroll
  for (int i = 0; i < OD; ++i) m += a[i];
  m *= (1.f/OD);
  float v = 0.f;
  #pragma unroll
  for (int i = 0; i < OD; ++i){ float d = a[i]-m; v += d*d; }
  v *= (1.f/OD);
  float scale = g_dec[j]*rsqrtf(v + 1e-5f);
  float sh = be_dec[j];
  #pragma unroll
  for (int i = 0; i < OD; ++i) Rn[(size_t)i*VV + j] = (a[i]-m)*scale + sh;
}

// ============ K13: per-row sums for softmax + cross-entropy ============
__global__ __launch_bounds__(256) void k13_reconB(const float* __restrict__ Rn,
    const float* __restrict__ br, float* __restrict__ rows){
  const int i = blockIdx.x;
  const int t = threadIdx.x;
  float s1 = 0.f, s2 = 0.f, s3 = 0.f;
  for (int j = t; j < VV; j += 256){
    float rn = Rn[(size_t)i*VV + j];
    float bv = br[(size_t)i*VV + j];
    s1 += __expf(rn);
    s2 += bv*rn;
    s3 += bv;
  }
  #pragma unroll
  for (int off = 32; off; off >>= 1){
    s1 += __shfl_down(s1, off, 64);
    s2 += __shfl_down(s2, off, 64);
    s3 += __shfl_down(s3, off, 64);
  }
  __shared__ float red[3][4];
  int lane = t & 63, w = t >> 6;
  if (lane == 0){ red[0][w] = s1; red[1][w] = s2; red[2][w] = s3; }
  __syncthreads();
  if (t == 0){
    rows[i]      = red[0][0]+red[0][1]+red[0][2]+red[0][3];
    rows[40 + i] = red[1][0]+red[1][1]+red[1][2]+red[1][3];
    rows[80 + i] = red[2][0]+red[2][1]+red[2][2]+red[2][3];
  }
}

// ============ K14: final losses ============
__global__ void k14_final(const float* __restrict__ rows, const float* __restrict__ scal,
    float* __restrict__ out){
  const int t = threadIdx.x;
  float v = 0.f;
  if (t < OD) v = rows[40 + t] - logf(rows[t]) * rows[80 + t];
  #pragma unroll
  for (int off = 32; off; off >>= 1) v += __shfl_down(v, off, 64);
  if (t == 0){
    float recon = -v * (1.f/OD);
    float tm = recon + scal[2];
    float ecr = 250.f * scal[3];
    out[0] = tm + ecr;
    out[1] = tm;
    out[2] = ecr;
  }
}

extern "C" void kernel_launch(void* const* d_in, const int* in_sizes, int n_in,
                              void* d_out, int out_size, void* d_ws, size_t ws_size,
                              hipStream_t stream){
  const float* bow   = (const float*)d_in[0];
  const float* epsn  = (const float*)d_in[1];
  const float* W1    = (const float*)d_in[2];
  const float* b1    = (const float*)d_in[3];
  const float* W2    = (const float*)d_in[4];
  const float* b2    = (const float*)d_in[5];
  const float* Wmu   = (const float*)d_in[6];
  const float* bmu   = (const float*)d_in[7];
  const float* Wlv   = (const float*)d_in[8];
  const float* blv   = (const float*)d_in[9];
  const float* g_mu  = (const float*)d_in[10];
  const float* be_mu = (const float*)d_in[11];
  const float* g_lv  = (const float*)d_in[12];
  const float* be_lv = (const float*)d_in[13];
  const float* g_dec = (const float*)d_in[14];
  const float* be_dec= (const float*)d_in[15];
  const float* wemb  = (const float*)d_in[16];
  const float* temb  = (const float*)d_in[17];
  const float* projV = (const float*)d_in[18];
  const float* projK = (const float*)d_in[19];
  char* ws = (char*)d_ws;
  float* r     = (float*)(ws + OFF_R);
  float* s     = (float*)(ws + OFF_S);
  float* scal  = (float*)(ws + OFF_SCAL);
  float* phiA  = (float*)(ws + OFF_PHIA);
  float* phiB  = (float*)(ws + OFF_PHIB);
  float* rows  = (float*)(ws + OFF_ROWS);
  float* parts = (float*)(ws + OFF_PARTS);
  float* mupre = (float*)(ws + OFF_MUPRE);
  float* lvpre = (float*)(ws + OFF_LVPRE);
  float* e1t   = (float*)(ws + OFF_E1T);
  float* e2t   = (float*)(ws + OFF_E2T);
  float* thred = (float*)(ws + OFF_THRED);
  float* br    = (float*)(ws + OFF_BOWRED);
  __hip_bfloat16* pvt = (__hip_bfloat16*)(ws + OFF_PVT);
  __hip_bfloat16* Xb  = (__hip_bfloat16*)(ws + OFF_XB);
  __half* Ce   = (__half*)(ws + OFF_CE);
  float* cost  = (float*)(ws + OFF_COST);
  float* Km    = (float*)(ws + OFF_KM);
  float* beta  = (float*)(ws + OFF_BETA);
  float* Rn    = (float*)(ws + OFF_RN);
  float* out   = (float*)d_out;

  hipMemsetAsync(d_ws, 0, ZERO_BYTES, stream);
  k1_stats<<<dim3(40, 8), 256, 0, stream>>>(bow, Xb, r, s);
  k2_eps<<<1, 256, 0, stream>>>(r, s, scal);
  k3_gemm<<<dim3(40, 40), 256, 0, stream>>>(Xb, r, scal, Ce);
  {
    float* pin = phiA; float* pout = phiB;
    for (int itr = 0; itr < 20; ++itr){
      k4_sweep<<<625, 256, 0, stream>>>(Ce, pin, pout);
      float* tmp = pin; pin = pout; pout = tmp;
    }
  }
  k5p_pvt<<<960, 256, 0, stream>>>(projV, pvt);
  k5_bowred<<<dim3(40, 16), 256, 0, stream>>>(Ce, phiA, pvt, br);
  k6_e1<<<50, 256, 0, stream>>>(br, W1, b1, e1t);
  k7_e2<<<50, 256, 0, stream>>>(e1t, W2, b2, e2t);
  k8a_mulv<<<8, 256, 0, stream>>>(e2t, Wmu, bmu, Wlv, blv, mupre, lvpre);
  k8b_theta<<<1, 256, 0, stream>>>(mupre, lvpre, g_mu, be_mu, g_lv, be_lv,
                                   epsn, projK, thred, out + 3, scal);
  k10_cost<<<79, 256, 0, stream>>>(temb, wemb, cost, Km, beta);
  k11_ecr<<<32, 256, 0, stream>>>(Km, cost, parts, scal);
  k12_reconA<<<20, 256, 0, stream>>>(thred, beta, g_dec, be_dec, Rn);
  k13_reconB<<<40, 256, 0, stream>>>(Rn, br, rows);
  k14_final<<<1, 64, 0, stream>>>(rows, scal, out);
}

// Round 4
// 1218.022 us; speedup vs baseline: 1.5120x; 1.5120x over previous
//
#include <hip/hip_runtime.h>
#include <hip/hip_bf16.h>
#include <hip/hip_fp16.h>

#define VV 5000
#define NTOP 50
#define ENH 200
#define NEMB 200
#define OD 40
#define MP 5120

typedef __attribute__((ext_vector_type(8))) short short8;
typedef __attribute__((ext_vector_type(4))) float f32x4;

// ---------------- workspace layout (bytes) ----------------
constexpr size_t OFF_R      = 0;          // 5000 f (atomic accum, zeroed)
constexpr size_t OFF_S      = 20224;      // 512 f (atomic accum, zeroed)
constexpr size_t OFF_SCAL   = 22528;      // 64 f: [0]=eps [1]=1/eps [2]=loss_KL [3]=ecr_dot
constexpr size_t OFF_PHIA   = 22784;      // 5000 f (zeroed = phi0)
constexpr size_t OFF_PHIB   = 43008;      // 5000 f
constexpr size_t OFF_ROWS   = 63232;      // S1[40] S2[40] S3[40]
constexpr size_t OFF_PARTS  = 63744;      // 2*16*64 f (ECR partials, dbl-buffered)
constexpr size_t OFF_FLAGS  = 71936;      // 16 ints, 64B apart (zeroed)
constexpr size_t OFF_MUPRE  = 72960;      // 50*40 f
constexpr size_t OFF_LVPRE  = 81152;
constexpr size_t OFF_E1T    = 89344;      // 200*40 f  [k][i]
constexpr size_t OFF_E2T    = 121600;
constexpr size_t OFF_THRED  = 153856;     // 40*50 f
constexpr size_t OFF_BOWRED = 162048;     // 40*5000 f (atomic accum, zeroed)
constexpr size_t ZERO_BYTES = 962304;     // everything below PVT is zeroed each call
constexpr size_t OFF_PVT    = 962304;     // 48*5120 bf16 (proj_V transposed, padded)
constexpr size_t OFF_XB     = 1453824;    // 5120*512 bf16 (bow.T, padded rows)
constexpr size_t OFF_CE     = 6696704;    // 5000*5000 fp16 (C/eps)
constexpr size_t OFF_COST   = 56696832;   // 50*5000 f
constexpr size_t OFF_KM     = 57697024;
constexpr size_t OFF_BETA   = 58697216;
constexpr size_t OFF_RN     = 59697408;   // 40*5000 f

// ============ K1: transpose bow -> Xb(bf16), row norms r, col sums s ============
__global__ __launch_bounds__(256) void k1_stats(const float* __restrict__ bow,
    __hip_bfloat16* __restrict__ Xb, float* __restrict__ r, float* __restrict__ s){
  __shared__ float lds[64][129];
  const int t = threadIdx.x;
  const int i0 = blockIdx.x * 128, d0 = blockIdx.y * 64;
  #pragma unroll
  for (int m = 0; m < 32; ++m){
    int idx = m*256 + t;
    int di = idx >> 7;
    int ii = idx & 127;
    int gi = i0 + ii;
    lds[di][ii] = (gi < VV) ? bow[(size_t)(d0+di)*VV + gi] : 0.f;
  }
  __syncthreads();
  if (t < 128 && (i0 + t) < VV){
    float acc = 0.f;
    for (int di = 0; di < 64; ++di){ float v = lds[di][t]; acc += v*v; }
    atomicAdd(&r[i0+t], acc);
  }
  if (t < 64){
    float acc = 0.f;
    for (int ii = 0; ii < 128; ++ii) acc += lds[t][ii];
    atomicAdd(&s[d0+t], acc);
  }
  __syncthreads();
  #pragma unroll
  for (int m = 0; m < 32; ++m){
    int idx = m*256 + t;
    int ii = idx >> 6;
    int dd = idx & 63;
    Xb[(size_t)(i0+ii)*512 + d0 + dd] = __float2bfloat16(lds[dd][ii]);
  }
}

// ============ K2: eps from closed-form mean(C) ============
__global__ __launch_bounds__(256) void k2_eps(const float* __restrict__ r,
    const float* __restrict__ s, float* __restrict__ scal){
  const int t = threadIdx.x;
  float a = 0.f, b = 0.f;
  for (int i = t; i < VV; i += 256) a += r[i];
  for (int d = t; d < 512; d += 256){ float v = s[d]; b += v*v; }
  #pragma unroll
  for (int off = 32; off; off >>= 1){
    a += __shfl_down(a, off, 64);
    b += __shfl_down(b, off, 64);
  }
  __shared__ float ra[4], rb[4];
  int lane = t & 63, w = t >> 6;
  if (lane == 0){ ra[w] = a; rb[w] = b; }
  __syncthreads();
  if (t == 0){
    float sa = ra[0]+ra[1]+ra[2]+ra[3];
    float sb = rb[0]+rb[1]+rb[2]+rb[3];
    float meanC = 2.f*sa/(float)VV - 2.f*sb/((float)VV*(float)VV);
    float eps = meanC / logf(30.f) + 1e-6f;
    scal[0] = eps;
    scal[1] = 1.f/eps;
  }
}

// ============ K3: Ce = (r_i + r_j - 2*X X^T)/eps as fp16, bf16 MFMA ============
__global__ __launch_bounds__(256) void k3_gemm(const __hip_bfloat16* __restrict__ Xb,
    const float* __restrict__ r, const float* __restrict__ scal, __half* __restrict__ Ce){
  __shared__ __hip_bfloat16 As[128*72];
  __shared__ __hip_bfloat16 Bs[128*72];
  const int t = threadIdx.x;
  const int i0 = blockIdx.x * 128, j0 = blockIdx.y * 128;
  const int lane = t & 63, w = t >> 6;
  const int wr = w >> 1, wc = w & 1;
  const int m16 = lane & 15, q4 = lane >> 4;
  f32x4 acc[4][4];
  #pragma unroll
  for (int a = 0; a < 4; ++a)
    #pragma unroll
    for (int b = 0; b < 4; ++b) acc[a][b] = (f32x4){0.f,0.f,0.f,0.f};
  const int srow = t >> 3, sseg = t & 7;
  for (int kc = 0; kc < 512; kc += 64){
    __syncthreads();
    #pragma unroll
    for (int m = 0; m < 4; ++m){
      int row = m*32 + srow;
      uint4 va = *(const uint4*)(Xb + (size_t)(i0+row)*512 + kc + sseg*8);
      *(uint4*)(As + row*72 + sseg*8) = va;
      uint4 vb = *(const uint4*)(Xb + (size_t)(j0+row)*512 + kc + sseg*8);
      *(uint4*)(Bs + row*72 + sseg*8) = vb;
    }
    __syncthreads();
    #pragma unroll
    for (int ks = 0; ks < 64; ks += 32){
      short8 af[4], bf[4];
      #pragma unroll
      for (int f = 0; f < 4; ++f){
        af[f] = *(const short8*)(As + (wr*64 + f*16 + m16)*72 + ks + q4*8);
        bf[f] = *(const short8*)(Bs + (wc*64 + f*16 + m16)*72 + ks + q4*8);
      }
      #pragma unroll
      for (int fr = 0; fr < 4; ++fr)
        #pragma unroll
        for (int fc = 0; fc < 4; ++fc)
          acc[fr][fc] = __builtin_amdgcn_mfma_f32_16x16x32_bf16(af[fr], bf[fc], acc[fr][fc], 0, 0, 0);
    }
  }
  const float inv_eps = scal[1];
  #pragma unroll
  for (int fr = 0; fr < 4; ++fr){
    int rbase = i0 + wr*64 + fr*16 + q4*4;
    #pragma unroll
    for (int fc = 0; fc < 4; ++fc){
      int col = j0 + wc*64 + fc*16 + m16;
      if (col < VV){
        float rc = r[col];
        #pragma unroll
        for (int q = 0; q < 4; ++q){
          int row = rbase + q;
          if (row < VV){
            float val = (r[row] + rc - 2.f*acc[fr][fc][q]) * inv_eps;
            Ce[(size_t)row*VV + col] = __float2half(val);
          }
        }
      }
    }
  }
}

// ============ K4: one symmetric-Sinkhorn sweep (phi = f/eps) ============
__global__ __launch_bounds__(256) void k4_sweep(const __half* __restrict__ Ce,
    const float* __restrict__ phi_in, float* __restrict__ phi_out){
  const int t = threadIdx.x;
  const int i0 = blockIdx.x * 8;
  float acc[8];
  #pragma unroll
  for (int rr = 0; rr < 8; ++rr) acc[rr] = 0.f;
  for (int c = t; c < 2500; c += 256){
    float2 ph = ((const float2*)phi_in)[c];
    #pragma unroll
    for (int rr = 0; rr < 8; ++rr){
      __half2 h2 = *((const __half2*)(Ce + (size_t)(i0+rr)*VV) + c);
      float2 ce = __half22float2(h2);
      acc[rr] += __expf(ph.x - ce.x) + __expf(ph.y - ce.y);
    }
  }
  #pragma unroll
  for (int rr = 0; rr < 8; ++rr)
    #pragma unroll
    for (int off = 32; off; off >>= 1)
      acc[rr] += __shfl_down(acc[rr], off, 64);
  __shared__ float red[4][8];
  int lane = t & 63, w = t >> 6;
  if (lane == 0){
    #pragma unroll
    for (int rr = 0; rr < 8; ++rr) red[w][rr] = acc[rr];
  }
  __syncthreads();
  if (t < 8){
    float ssum = red[0][t] + red[1][t] + red[2][t] + red[3][t];
    const float loga = -8.517193191416238f;   // -log(5000)
    float lse = __logf(ssum);
    phi_out[i0 + t] = 0.5f*(phi_in[i0 + t] + loga - lse);
  }
}

// ============ K5p: proj_V -> transposed padded bf16 [48][5120] ============
__global__ __launch_bounds__(256) void k5p_pvt(const float* __restrict__ projV,
    __hip_bfloat16* __restrict__ pvt){
  int idx = blockIdx.x*256 + threadIdx.x;
  if (idx >= 48*MP) return;
  int n = idx / MP, j = idx - n*MP;
  float v = (n < OD && j < VV) ? projV[(size_t)j*OD + n] : 0.f;
  pvt[idx] = __float2bfloat16(v);
}

// ============ K5: bow_reduced = (P @ proj_V)^T via MFMA, P on the fly ============
__global__ __launch_bounds__(256) void k5_bowred(const __half* __restrict__ Ce,
    const float* __restrict__ phi, const __hip_bfloat16* __restrict__ pvt,
    float* __restrict__ br){
  __shared__ __hip_bfloat16 As[128*72];
  __shared__ __hip_bfloat16 Bs[48*72];
  const int t = threadIdx.x;
  const int i0 = blockIdx.x * 128;
  const int k0 = blockIdx.y * 320;
  const int lane = t & 63, w = t >> 6;
  const int m16 = lane & 15, q4 = lane >> 4;
  f32x4 acc[2][3];
  #pragma unroll
  for (int a = 0; a < 2; ++a)
    #pragma unroll
    for (int b = 0; b < 3; ++b) acc[a][b] = (f32x4){0.f,0.f,0.f,0.f};
  for (int kc = k0; kc < k0 + 320; kc += 64){
    __syncthreads();
    #pragma unroll
    for (int m = 0; m < 32; ++m){
      int idx = m*256 + t;
      int row = idx >> 6, c = idx & 63;
      int gi = i0 + row, j2 = kc + c;
      float p = 0.f;
      if (gi < VV && j2 < VV){
        float ce = __half2float(Ce[(size_t)gi*VV + j2]);
        p = __expf(phi[gi] + phi[j2] - ce);
      }
      As[row*72 + c] = __float2bfloat16(p);
    }
    #pragma unroll
    for (int m = 0; m < 12; ++m){
      int idx = m*256 + t;
      int row = idx >> 6, c = idx & 63;
      Bs[row*72 + c] = pvt[(size_t)row*MP + kc + c];
    }
    __syncthreads();
    #pragma unroll
    for (int ks = 0; ks < 64; ks += 32){
      short8 af[2], bf[3];
      #pragma unroll
      for (int f = 0; f < 2; ++f)
        af[f] = *(const short8*)(As + (w*32 + f*16 + m16)*72 + ks + q4*8);
      #pragma unroll
      for (int f = 0; f < 3; ++f)
        bf[f] = *(const short8*)(Bs + (f*16 + m16)*72 + ks + q4*8);
      #pragma unroll
      for (int fr = 0; fr < 2; ++fr)
        #pragma unroll
        for (int fc = 0; fc < 3; ++fc)
          acc[fr][fc] = __builtin_amdgcn_mfma_f32_16x16x32_bf16(af[fr], bf[fc], acc[fr][fc], 0, 0, 0);
    }
  }
  #pragma unroll
  for (int fr = 0; fr < 2; ++fr){
    int rbase = i0 + w*32 + fr*16 + q4*4;
    #pragma unroll
    for (int fc = 0; fc < 3; ++fc){
      int col = fc*16 + m16;
      if (col < OD){
        #pragma unroll
        for (int q = 0; q < 4; ++q){
          int row = rbase + q;
          if (row < VV) atomicAdd(&br[(size_t)col*VV + row], acc[fr][fc][q]);
        }
      }
    }
  }
}

// ============ K6: e1^T = softplus(bow_reduced @ W1^T + b1) ============
__global__ __launch_bounds__(256) void k6_e1(const float* __restrict__ br,
    const float* __restrict__ W1, const float* __restrict__ b1, float* __restrict__ e1t){
  const int t = threadIdx.x;
  const int lane = t & 63, w = t >> 6;
  const int k = blockIdx.x*4 + w;
  float acc[OD];
  #pragma unroll
  for (int i = 0; i < OD; ++i) acc[i] = 0.f;
  const float4* w4p = (const float4*)(W1 + (size_t)k*VV);
  for (int f4 = lane; f4 < 1250; f4 += 64){
    float4 wv = w4p[f4];
    #pragma unroll
    for (int i = 0; i < OD; ++i){
      float4 bv = ((const float4*)(br + (size_t)i*VV))[f4];
      acc[i] += bv.x*wv.x + bv.y*wv.y + bv.z*wv.z + bv.w*wv.w;
    }
  }
  #pragma unroll
  for (int i = 0; i < OD; ++i)
    #pragma unroll
    for (int off = 32; off; off >>= 1)
      acc[i] += __shfl_down(acc[i], off, 64);
  __shared__ float red[4][OD];
  if (lane == 0){
    #pragma unroll
    for (int i = 0; i < OD; ++i) red[w][i] = acc[i];
  }
  __syncthreads();
  if (t < 160){
    int ww = t / OD, i = t - ww*OD;
    int kk = blockIdx.x*4 + ww;
    float x = red[ww][i] + b1[kk];
    float sp = (x > 20.f) ? x : log1pf(__expf(x));
    e1t[kk*OD + i] = sp;
  }
}

// ============ K7: e2^T = softplus(e1 @ W2^T + b2) ============
__global__ __launch_bounds__(256) void k7_e2(const float* __restrict__ e1t,
    const float* __restrict__ W2, const float* __restrict__ b2, float* __restrict__ e2t){
  const int t = threadIdx.x;
  const int lane = t & 63, w = t >> 6;
  const int k = blockIdx.x*4 + w;
  float acc[OD];
  #pragma unroll
  for (int i = 0; i < OD; ++i) acc[i] = 0.f;
  for (int j = lane; j < ENH; j += 64){
    float wv = W2[(size_t)k*ENH + j];
    #pragma unroll
    for (int i = 0; i < OD; ++i) acc[i] += e1t[j*OD + i] * wv;
  }
  #pragma unroll
  for (int i = 0; i < OD; ++i)
    #pragma unroll
    for (int off = 32; off; off >>= 1)
      acc[i] += __shfl_down(acc[i], off, 64);
  __shared__ float red[4][OD];
  if (lane == 0){
    #pragma unroll
    for (int i = 0; i < OD; ++i) red[w][i] = acc[i];
  }
  __syncthreads();
  if (t < 160){
    int ww = t / OD, i = t - ww*OD;
    int kk = blockIdx.x*4 + ww;
    float x = red[ww][i] + b2[kk];
    float sp = (x > 20.f) ? x : log1pf(__expf(x));
    e2t[kk*OD + i] = sp;
  }
}

// ============ K8a: mu_pre/lv_pre (stored [t50][i]) ============
__global__ __launch_bounds__(256) void k8a_mulv(const float* __restrict__ e2t,
    const float* __restrict__ Wmu, const float* __restrict__ bmu,
    const float* __restrict__ Wlv, const float* __restrict__ blv,
    float* __restrict__ mupre, float* __restrict__ lvpre){
  int id = blockIdx.x*256 + threadIdx.x;
  if (id >= NTOP*OD) return;
  int t50 = id / OD, i = id - t50*OD;
  float am = 0.f, al = 0.f;
  for (int kk = 0; kk < ENH; ++kk){
    float e = e2t[kk*OD + i];
    am += e * Wmu[t50*ENH + kk];
    al += e * Wlv[t50*ENH + kk];
  }
  mupre[t50*OD + i] = am + bmu[t50];
  lvpre[t50*OD + i] = al + blv[t50];
}

// ============ K8b: BN + KL + z/theta + small SNE(50) + theta_reduced (single WG) ============
__global__ __launch_bounds__(256) void k8b_theta(const float* __restrict__ mupre,
    const float* __restrict__ lvpre,
    const float* __restrict__ g_mu, const float* __restrict__ be_mu,
    const float* __restrict__ g_lv, const float* __restrict__ be_lv,
    const float* __restrict__ eps_noise, const float* __restrict__ projK,
    float* __restrict__ thred, float* __restrict__ d_out3, float* __restrict__ scal){
  __shared__ float mu[NTOP][OD];
  __shared__ float lv[NTOP][OD];
  __shared__ float th[OD][NTOP];
  __shared__ float C2[NTOP][NTOP];
  __shared__ float P2[NTOP][NTOP];
  __shared__ float f2[NTOP], nf[NTOP];
  __shared__ float sred[4];
  __shared__ float eps2s[2];
  const int t = threadIdx.x;
  if (t < NTOP){
    float m = 0.f;
    for (int i = 0; i < OD; ++i) m += mupre[t*OD + i];
    m *= (1.f/OD);
    float v = 0.f;
    for (int i = 0; i < OD; ++i){ float d = mupre[t*OD+i] - m; v += d*d; }
    v *= (1.f/OD);
    float sc = g_mu[t] * rsqrtf(v + 1e-5f);
    float sh = be_mu[t];
    for (int i = 0; i < OD; ++i) mu[t][i] = (mupre[t*OD+i] - m)*sc + sh;
    m = 0.f;
    for (int i = 0; i < OD; ++i) m += lvpre[t*OD + i];
    m *= (1.f/OD);
    v = 0.f;
    for (int i = 0; i < OD; ++i){ float d = lvpre[t*OD+i] - m; v += d*d; }
    v *= (1.f/OD);
    sc = g_lv[t] * rsqrtf(v + 1e-5f);
    sh = be_lv[t];
    for (int i = 0; i < OD; ++i) lv[t][i] = (lvpre[t*OD+i] - m)*sc + sh;
  }
  __syncthreads();
  { // KL divergence
    float kl = 0.f;
    if (t < OD){
      const float var2 = 1.f - 1.f/(float)NTOP;
      const float lv2 = logf(var2);
      float ssum = 0.f;
      for (int q = 0; q < NTOP; ++q){
        float l = lv[q][t];
        float m = mu[q][t];
        ssum += (__expf(l) + m*m)/var2 + lv2 - l;
      }
      kl = 0.5f*(ssum - (float)NTOP);
    }
    #pragma unroll
    for (int off = 32; off; off >>= 1) kl += __shfl_down(kl, off, 64);
    if ((t & 63) == 0) sred[t >> 6] = kl;
    __syncthreads();
    if (t == 0) scal[2] = (sred[0]+sred[1]+sred[2]+sred[3]) * (1.f/OD);
    __syncthreads();
  }
  if (t < OD){ // z + softmax
    float z[NTOP];
    float mx = -1e30f;
    for (int q = 0; q < NTOP; ++q){
      float val = mu[q][t] + eps_noise[t*NTOP + q]*__expf(0.5f*lv[q][t]);
      z[q] = val;
      mx = fmaxf(mx, val);
    }
    float ssum = 0.f;
    for (int q = 0; q < NTOP; ++q){ float e = __expf(z[q]-mx); z[q] = e; ssum += e; }
    float inv = 1.f/ssum;
    for (int q = 0; q < NTOP; ++q) th[t][q] = z[q]*inv;
  }
  __syncthreads();
  { // C2 + mean
    float csum = 0.f;
    for (int pr = t; pr < NTOP*NTOP; pr += 256){
      int a = pr / NTOP, b = pr - (pr/NTOP)*NTOP;
      float ss = 0.f;
      for (int i = 0; i < OD; ++i){ float d = th[i][a] - th[i][b]; ss += d*d; }
      C2[a][b] = ss;
      csum += ss;
    }
    #pragma unroll
    for (int off = 32; off; off >>= 1) csum += __shfl_down(csum, off, 64);
    if ((t & 63) == 0) sred[t >> 6] = csum;
    __syncthreads();
    if (t == 0){
      float meanC = (sred[0]+sred[1]+sred[2]+sred[3]) / ((float)NTOP*NTOP);
      float e2 = meanC / logf(30.f) + 1e-6f;
      eps2s[0] = e2; eps2s[1] = 1.f/e2;
    }
  }
  if (t < NTOP) f2[t] = 0.f;
  __syncthreads();
  const float loga2 = -logf((float)NTOP);
  for (int it = 0; it < 20; ++it){
    if (t < NTOP){
      float ie = eps2s[1];
      float ssum = 0.f;
      for (int sI = 0; sI < NTOP; ++sI)
        ssum += __expf((f2[sI] - C2[t][sI]) * ie);
      float lse = __logf(ssum);
      nf[t] = 0.5f*(f2[t] + eps2s[0]*(loga2 - lse));
    }
    __syncthreads();
    if (t < NTOP) f2[t] = nf[t];
    __syncthreads();
  }
  for (int pr = t; pr < NTOP*NTOP; pr += 256){
    int a = pr / NTOP, b = pr - (pr/NTOP)*NTOP;
    P2[a][b] = __expf((f2[a] + f2[b] - C2[a][b]) * eps2s[1]);
  }
  __syncthreads();
  for (int o = t; o < NTOP*OD; o += 256){
    int t50 = o / OD, kk = o - (o/OD)*OD;
    float ssum = 0.f;
    for (int sI = 0; sI < NTOP; ++sI)
      ssum += P2[t50][sI] * projK[sI*OD + kk];
    thred[kk*NTOP + t50] = ssum;
    d_out3[kk*NTOP + t50] = ssum;
  }
}

// ============ K10: cost, Km=exp(-20c), beta=softmax(-5c over topics) ============
__global__ __launch_bounds__(256) void k10_cost(const float* __restrict__ temb,
    const float* __restrict__ wemb, float* __restrict__ cost, float* __restrict__ Km,
    float* __restrict__ beta){
  __shared__ float Tt[100][52];
  __shared__ float wed[100][68];
  __shared__ float sc[52][64];
  __shared__ float tn[52];
  __shared__ float wn[64];
  const int t = threadIdx.x;
  const int j0 = blockIdx.x * 64;
  const int tg = t >> 4, jg = t & 15;
  float am[4][4];
  #pragma unroll
  for (int a = 0; a < 4; ++a)
    #pragma unroll
    for (int b = 0; b < 4; ++b) am[a][b] = 0.f;
  float tnp = 0.f, wnp = 0.f;
  for (int c = 0; c < 2; ++c){
    __syncthreads();
    const int dbase = c*100;
    for (int idx = t; idx < NTOP*100; idx += 256){
      int t50 = idx / 100, d = idx - t50*100;
      Tt[d][t50] = temb[t50*NEMB + dbase + d];
    }
    for (int idx = t; idx < 64*100; idx += 256){
      int j = idx / 100, d = idx - j*100;
      int gj = j0 + j;
      wed[d][j] = (gj < VV) ? wemb[(size_t)gj*NEMB + dbase + d] : 0.f;
    }
    __syncthreads();
    if (t < NTOP){
      float a = 0.f;
      for (int d = 0; d < 100; ++d){ float v = Tt[d][t]; a += v*v; }
      tnp += a;
    }
    if (t >= 64 && t < 128){
      int j = t - 64;
      float a = 0.f;
      for (int d = 0; d < 100; ++d){ float v = wed[d][j]; a += v*v; }
      wnp += a;
    }
    if (t < 208){
      for (int d = 0; d < 100; ++d){
        const float4 tv = *(const float4*)(&Tt[d][tg*4]);
        const float4 wv = *(const float4*)(&wed[d][jg*4]);
        am[0][0] += tv.x*wv.x; am[0][1] += tv.x*wv.y; am[0][2] += tv.x*wv.z; am[0][3] += tv.x*wv.w;
        am[1][0] += tv.y*wv.x; am[1][1] += tv.y*wv.y; am[1][2] += tv.y*wv.z; am[1][3] += tv.y*wv.w;
        am[2][0] += tv.z*wv.x; am[2][1] += tv.z*wv.y; am[2][2] += tv.z*wv.z; am[2][3] += tv.z*wv.w;
        am[3][0] += tv.w*wv.x; am[3][1] += tv.w*wv.y; am[3][2] += tv.w*wv.z; am[3][3] += tv.w*wv.w;
      }
    }
  }
  if (t < NTOP) tn[t] = tnp;
  if (t >= 64 && t < 128) wn[t-64] = wnp;
  __syncthreads();
  if (t < 208){
    #pragma unroll
    for (int a = 0; a < 4; ++a){
      int t50 = tg*4 + a;
      if (t50 < NTOP){
        float tv = tn[t50];
        float cc[4];
        #pragma unroll
        for (int b = 0; b < 4; ++b) cc[b] = tv + wn[jg*4+b] - 2.f*am[a][b];
        int gj = j0 + jg*4;
        if (gj + 3 < VV){
          *(float4*)(cost + (size_t)t50*VV + gj) = make_float4(cc[0],cc[1],cc[2],cc[3]);
          *(float4*)(Km + (size_t)t50*VV + gj) =
              make_float4(__expf(-20.f*cc[0]), __expf(-20.f*cc[1]),
                          __expf(-20.f*cc[2]), __expf(-20.f*cc[3]));
        }
        #pragma unroll
        for (int b = 0; b < 4; ++b) sc[t50][jg*4+b] = -5.f*cc[b];
      }
    }
  }
  __syncthreads();
  if (t < 64){
    int gj = j0 + t;
    if (gj < VV){
      float mx = -1e30f;
      for (int q = 0; q < NTOP; ++q) mx = fmaxf(mx, sc[q][t]);
      float ssum = 0.f;
      for (int q = 0; q < NTOP; ++q){ float e = __expf(sc[q][t]-mx); sc[q][t] = e; ssum += e; }
      float inv = 1.f/ssum;
      for (int q = 0; q < NTOP; ++q) beta[(size_t)q*VV + gj] = sc[q][t]*inv;
    }
  }
}

// ============ K11: ECR Sinkhorn, 16 co-resident WGs, flag-sync per iteration ============
// Km slice lives in LDS as fp16, column-scaled by 1/colmax (Sinkhorn is exactly
// invariant under per-column scaling of Km — gauge freedom; only fp16 rounding
// remains, ~0.05% per entry). No register spills (R1 had 163 floats/thread vs
// 120 VGPRs). Sync protocol is R1's proven shape: store 50 partials + release
// flag; t<16 polls 16 flags (one load instr/round); bulk partial read once.
__global__ __launch_bounds__(256) void k11_ecr(const float* __restrict__ Km,
    const float* __restrict__ cost, float* __restrict__ parts, int* __restrict__ flags,
    float* __restrict__ scal){
  const int t = threadIdx.x;
  const int b = blockIdx.x;                       // 0..15
  const int base = (b < 8) ? b*313 : 2504 + (b-8)*312;
  const int sz   = (b < 8) ? 313 : 312;
  // stride 322 halfs = 161 floats; 161 mod 32 = 1 -> conflict-free row access
  __shared__ __half KmL[50*322];
  __shared__ __align__(16) float varr[320];
  __shared__ float us[52];
  __shared__ float p5[5][52];
  __shared__ float redr[4];
  // ---- load + column-scale Km slice into fp16 LDS ----
  for (int c = t; c < 322; c += 256){
    if (c < sz){
      float col[50];
      float mx = 0.f;
      #pragma unroll
      for (int q = 0; q < NTOP; ++q){
        col[q] = Km[(size_t)q*VV + base + c];
        mx = fmaxf(mx, col[q]);
      }
      float inv = 1.f/(mx + 1e-30f);
      #pragma unroll
      for (int q = 0; q < NTOP; ++q)
        KmL[q*322 + c] = __float2half(col[q]*inv);
    } else {
      #pragma unroll
      for (int q = 0; q < NTOP; ++q) KmL[q*322 + c] = __float2half(0.f);
    }
  }
  if (t < 52) us[t] = (t < NTOP) ? (1.f/(float)NTOP) : 0.f;
  for (int c = sz + t; c < 320; c += 256) varr[c] = 0.f;
  __syncthreads();
  const bool act = (2*t < sz);
  for (int it = 0; it < 100; ++it){
    // phase 1: v'_j = (1/V) / (Kn^T u + 1e-16) for cols 2t, 2t+1
    if (act){
      float w0 = 0.f, w1 = 0.f, w2 = 0.f, w3 = 0.f;
      #pragma unroll
      for (int q = 0; q < NTOP; q += 2){
        float u0 = us[q], u1 = us[q+1];
        float2 f0 = __half22float2(*(const __half2*)(KmL + q*322 + 2*t));
        float2 f1 = __half22float2(*(const __half2*)(KmL + (q+1)*322 + 2*t));
        w0 += f0.x*u0; w1 += f0.y*u0;
        w2 += f1.x*u1; w3 += f1.y*u1;
      }
      float2 vv;
      vv.x = (1.f/(float)VV)/((w0+w2) + 1e-16f);
      vv.y = (2*t+1 < sz) ? (1.f/(float)VV)/((w1+w3) + 1e-16f) : 0.f;
      *(float2*)(varr + 2*t) = vv;
    }
    __syncthreads();
    // phase 2: per-topic partial of Kn v' over this slice
    if (t < 250){
      const int qq = t % NTOP, stripe = t / NTOP;
      const __half* kp = KmL + qq*322 + stripe*64;
      const float* vp = varr + stripe*64;
      float s0 = 0.f, s1 = 0.f, s2 = 0.f, s3 = 0.f;
      #pragma unroll
      for (int n = 0; n < 64; n += 4){
        float2 fa = __half22float2(*(const __half2*)(kp + n));
        float2 fb = __half22float2(*(const __half2*)(kp + n + 2));
        float4 v4 = *(const float4*)(vp + n);
        s0 += fa.x*v4.x; s1 += fa.y*v4.y; s2 += fb.x*v4.z; s3 += fb.y*v4.w;
      }
      p5[stripe][qq] = (s0+s1)+(s2+s3);
    }
    __syncthreads();
    if (t < NTOP){
      float sm = p5[0][t]+p5[1][t]+p5[2][t]+p5[3][t]+p5[4][t];
      __hip_atomic_store(&parts[(size_t)(it & 1)*1024 + b*64 + t], sm,
                         __ATOMIC_RELAXED, __HIP_MEMORY_SCOPE_AGENT);
    }
    if (t == 0)
      __hip_atomic_store(&flags[b*16], it+1, __ATOMIC_RELEASE, __HIP_MEMORY_SCOPE_AGENT);
    if (t < 16){
      while (__hip_atomic_load(&flags[t*16], __ATOMIC_ACQUIRE, __HIP_MEMORY_SCOPE_AGENT) <= it)
        __builtin_amdgcn_s_sleep(2);
    }
    if (t < NTOP){
      float sm = 0.f;
      #pragma unroll
      for (int wgi = 0; wgi < 16; ++wgi)
        sm += __hip_atomic_load(&parts[(size_t)(it & 1)*1024 + wgi*64 + t],
                                __ATOMIC_RELAXED, __HIP_MEMORY_SCOPE_AGENT);
      us[t] = (1.f/(float)NTOP)/(sm + 1e-16f);
    }
    __syncthreads();
  }
  // final: v' from final u, partial of sum(u * Kn * v'^T * cost)  (gauge-exact)
  float lsum = 0.f;
  if (act){
    float w0 = 0.f, w1 = 0.f, w2 = 0.f, w3 = 0.f;
    #pragma unroll
    for (int q = 0; q < NTOP; q += 2){
      float u0 = us[q], u1 = us[q+1];
      float2 f0 = __half22float2(*(const __half2*)(KmL + q*322 + 2*t));
      float2 f1 = __half22float2(*(const __half2*)(KmL + (q+1)*322 + 2*t));
      w0 += f0.x*u0; w1 += f0.y*u0;
      w2 += f1.x*u1; w3 += f1.y*u1;
    }
    float v0 = (1.f/(float)VV)/((w0+w2) + 1e-16f);
    const bool ok1 = (2*t+1 < sz);
    float v1 = ok1 ? (1.f/(float)VV)/((w1+w3) + 1e-16f) : 0.f;
    float acc = 0.f;
    #pragma unroll
    for (int q = 0; q < NTOP; ++q){
      float2 f = __half22float2(*(const __half2*)(KmL + q*322 + 2*t));
      float uq = us[q];
      float c0 = cost[(size_t)q*VV + base + 2*t];
      acc += uq*f.x*v0*c0;
      if (ok1){
        float c1 = cost[(size_t)q*VV + base + 2*t + 1];
        acc += uq*f.y*v1*c1;
      }
    }
    lsum = acc;
  }
  #pragma unroll
  for (int off = 32; off; off >>= 1) lsum += __shfl_down(lsum, off, 64);
  if ((t & 63) == 0) redr[t >> 6] = lsum;
  __syncthreads();
  if (t == 0) atomicAdd(&scal[3], redr[0]+redr[1]+redr[2]+redr[3]);
}

// ============ K12: R = theta_red @ beta, column BN ============
__global__ __launch_bounds__(256) void k12_reconA(const float* __restrict__ thred,
    const float* __restrict__ beta, const float* __restrict__ g_dec,
    const float* __restrict__ be_dec, float* __restrict__ Rn){
  __shared__ float trs[OD][NTOP];
  const int t = threadIdx.x;
  for (int o = t; o < OD*NTOP; o += 256) trs[o/NTOP][o - (o/NTOP)*NTOP] = thred[o];
  __syncthreads();
  int j = blockIdx.x*256 + t;
  if (j >= VV) return;
  float a[OD];
  #pragma unroll
  for (int i = 0; i < OD; ++i) a[i] = 0.f;
  for (int q = 0; q < NTOP; ++q){
    float bv = beta[(size_t)q*VV + j];
    #pragma unroll
    for (int i = 0; i < OD; ++i) a[i] += trs[i][q]*bv;
  }
  float m = 0.f;
  #pragma unroll
  for (int i = 0; i < OD; ++i) m += a[i];
  m *= (1.f/OD);
  float v = 0.f;
  #pragma unroll
  for (int i = 0; i < OD; ++i){ float d = a[i]-m; v += d*d; }
  v *= (1.f/OD);
  float scale = g_dec[j]*rsqrtf(v + 1e-5f);
  float sh = be_dec[j];
  #pragma unroll
  for (int i = 0; i < OD; ++i) Rn[(size_t)i*VV + j] = (a[i]-m)*scale + sh;
}

// ============ K13: per-row sums for softmax + cross-entropy ============
__global__ __launch_bounds__(256) void k13_reconB(const float* __restrict__ Rn,
    const float* __restrict__ br, float* __restrict__ rows){
  const int i = blockIdx.x;
  const int t = threadIdx.x;
  float s1 = 0.f, s2 = 0.f, s3 = 0.f;
  for (int j = t; j < VV; j += 256){
    float rn = Rn[(size_t)i*VV + j];
    float bv = br[(size_t)i*VV + j];
    s1 += __expf(rn);
    s2 += bv*rn;
    s3 += bv;
  }
  #pragma unroll
  for (int off = 32; off; off >>= 1){
    s1 += __shfl_down(s1, off, 64);
    s2 += __shfl_down(s2, off, 64);
    s3 += __shfl_down(s3, off, 64);
  }
  __shared__ float red[3][4];
  int lane = t & 63, w = t >> 6;
  if (lane == 0){ red[0][w] = s1; red[1][w] = s2; red[2][w] = s3; }
  __syncthreads();
  if (t == 0){
    rows[i]      = red[0][0]+red[0][1]+red[0][2]+red[0][3];
    rows[40 + i] = red[1][0]+red[1][1]+red[1][2]+red[1][3];
    rows[80 + i] = red[2][0]+red[2][1]+red[2][2]+red[2][3];
  }
}

// ============ K14: final losses ============
__global__ void k14_final(const float* __restrict__ rows, const float* __restrict__ scal,
    float* __restrict__ out){
  const int t = threadIdx.x;
  float v = 0.f;
  if (t < OD) v = rows[40 + t] - logf(rows[t]) * rows[80 + t];
  #pragma unroll
  for (int off = 32; off; off >>= 1) v += __shfl_down(v, off, 64);
  if (t == 0){
    float recon = -v * (1.f/OD);
    float tm = recon + scal[2];
    float ecr = 250.f * scal[3];
    out[0] = tm + ecr;
    out[1] = tm;
    out[2] = ecr;
  }
}

extern "C" void kernel_launch(void* const* d_in, const int* in_sizes, int n_in,
                              void* d_out, int out_size, void* d_ws, size_t ws_size,
                              hipStream_t stream){
  const float* bow   = (const float*)d_in[0];
  const float* epsn  = (const float*)d_in[1];
  const float* W1    = (const float*)d_in[2];
  const float* b1    = (const float*)d_in[3];
  const float* W2    = (const float*)d_in[4];
  const float* b2    = (const float*)d_in[5];
  const float* Wmu   = (const float*)d_in[6];
  const float* bmu   = (const float*)d_in[7];
  const float* Wlv   = (const float*)d_in[8];
  const float* blv   = (const float*)d_in[9];
  const float* g_mu  = (const float*)d_in[10];
  const float* be_mu = (const float*)d_in[11];
  const float* g_lv  = (const float*)d_in[12];
  const float* be_lv = (const float*)d_in[13];
  const float* g_dec = (const float*)d_in[14];
  const float* be_dec= (const float*)d_in[15];
  const float* wemb  = (const float*)d_in[16];
  const float* temb  = (const float*)d_in[17];
  const float* projV = (const float*)d_in[18];
  const float* projK = (const float*)d_in[19];
  char* ws = (char*)d_ws;
  float* r     = (float*)(ws + OFF_R);
  float* s     = (float*)(ws + OFF_S);
  float* scal  = (float*)(ws + OFF_SCAL);
  float* phiA  = (float*)(ws + OFF_PHIA);
  float* phiB  = (float*)(ws + OFF_PHIB);
  float* rows  = (float*)(ws + OFF_ROWS);
  float* parts = (float*)(ws + OFF_PARTS);
  int*   flags = (int*)(ws + OFF_FLAGS);
  float* mupre = (float*)(ws + OFF_MUPRE);
  float* lvpre = (float*)(ws + OFF_LVPRE);
  float* e1t   = (float*)(ws + OFF_E1T);
  float* e2t   = (float*)(ws + OFF_E2T);
  float* thred = (float*)(ws + OFF_THRED);
  float* br    = (float*)(ws + OFF_BOWRED);
  __hip_bfloat16* pvt = (__hip_bfloat16*)(ws + OFF_PVT);
  __hip_bfloat16* Xb  = (__hip_bfloat16*)(ws + OFF_XB);
  __half* Ce   = (__half*)(ws + OFF_CE);
  float* cost  = (float*)(ws + OFF_COST);
  float* Km    = (float*)(ws + OFF_KM);
  float* beta  = (float*)(ws + OFF_BETA);
  float* Rn    = (float*)(ws + OFF_RN);
  float* out   = (float*)d_out;

  hipMemsetAsync(d_ws, 0, ZERO_BYTES, stream);
  k1_stats<<<dim3(40, 8), 256, 0, stream>>>(bow, Xb, r, s);
  k2_eps<<<1, 256, 0, stream>>>(r, s, scal);
  k3_gemm<<<dim3(40, 40), 256, 0, stream>>>(Xb, r, scal, Ce);
  {
    float* pin = phiA; float* pout = phiB;
    for (int itr = 0; itr < 20; ++itr){
      k4_sweep<<<625, 256, 0, stream>>>(Ce, pin, pout);
      float* tmp = pin; pin = pout; pout = tmp;
    }
  }
  k5p_pvt<<<960, 256, 0, stream>>>(projV, pvt);
  k5_bowred<<<dim3(40, 16), 256, 0, stream>>>(Ce, phiA, pvt, br);
  k6_e1<<<50, 256, 0, stream>>>(br, W1, b1, e1t);
  k7_e2<<<50, 256, 0, stream>>>(e1t, W2, b2, e2t);
  k8a_mulv<<<8, 256, 0, stream>>>(e2t, Wmu, bmu, Wlv, blv, mupre, lvpre);
  k8b_theta<<<1, 256, 0, stream>>>(mupre, lvpre, g_mu, be_mu, g_lv, be_lv,
                                   epsn, projK, thred, out + 3, scal);
  k10_cost<<<79, 256, 0, stream>>>(temb, wemb, cost, Km, beta);
  k11_ecr<<<16, 256, 0, stream>>>(Km, cost, parts, flags, scal);
  k12_reconA<<<20, 256, 0, stream>>>(thred, beta, g_dec, be_dec, Rn);
  k13_reconB<<<40, 256, 0, stream>>>(Rn, br, rows);
  k14_final<<<1, 64, 0, stream>>>(rows, scal, out);
}